// Round 13
// baseline (105.797 us; speedup 1.0000x reference)
//
#include <hip/hip_runtime.h>
#include <float.h>

// VectorQuantizer: x [64,64,32,32] f32, weight [1024,64] f32
// out[n] = weight[argmin_k ||x_n - w_k||^2]
// score = 0.5||w||^2 + (-x).w via split-bf16 MFMA (6-step, lo*lo dropped).
// R25 = R24 (best, 45.0us) + two work/drain removals:
//   (1) EARLY chunk-0 DMA: LDS re-layout so wbuf1 [34816,67584) does NOT
//       alias XE [0,34816). Chunk 0 issues at kernel start into wbuf1 and
//       streams under the whole conversion phase; first loop barrier no
//       longer eats the 32KB DMA. Parity: even chunks->wbuf1, odd->wbuf0.
//       One standalone barrier deleted (loop-top barrier doubles as the
//       XE-death sync). ambn init moved into epilogue (slot aliases XE).
//   (2) vq_prep coalesced: each lane computes the two shorts at ITS OWN
//       output dword via inverse swizzle (logical seg = phys ^ (k&15)),
//       one 4B store/lane (256B/wave) instead of 128 scattered 2B stores.
//       Bit-identical output.
// Session model: all pipes 5-20% of ceiling, occupancy-insensitive,
// work-proportional => issue/work-bound (likely DVFS-reduced clock);
// only instruction/drain removal pays. R24 deltas kept: eps 5e-4+1e-5|B1|,
// wnl in LDS, unroll 2, 6-step product, short8 XE writes, redk-less
// epilogue, inline exact rescue.
#define NLAT   65536
#define KCODES 1024
#define DIM    64
#define HW     1024
#define LPB    128
#define CPK    128
#define NCHUNK 8
#define XROW   136          // XE padded row (shorts): 272 B

typedef float f32x4 __attribute__((ext_vector_type(4)));
typedef short short8 __attribute__((ext_vector_type(8)));

static __device__ __forceinline__ unsigned short f2bf(float f) {
    unsigned int u = __float_as_uint(f);
    return (unsigned short)((u + 0x7fffu + ((u >> 16) & 1u)) >> 16);   // RNE
}
static __device__ __forceinline__ float bf2f(unsigned short h) {
    return __uint_as_float(((unsigned int)h) << 16);
}
static __device__ __forceinline__ void async_cp16(const void* g, void* l) {
    __builtin_amdgcn_global_load_lds(
        (const __attribute__((address_space(1))) unsigned int*)g,
        (__attribute__((address_space(3))) unsigned int*)l, 16, 0, 0);
}

// ---------------------------------------------------------------------------
// Prep: one WAVE per code (grid 256 x 256 thr). Lane d loads w[k][d]
// (coalesced), shuffle-reduces the norm. Output row (XOR-swizzled): each
// lane computes the two shorts at its own dword via the INVERSE swizzle
// (logical seg = phys seg ^ (k&15); logical<8 -> hi(d), else lo(d)) and
// issues one coalesced 4B store. Bit-identical to the scatter version.
__global__ __launch_bounds__(256)
void vq_prep(const float* __restrict__ w, unsigned short* __restrict__ WEg,
             float* __restrict__ wn) {
    const int wave = threadIdx.x >> 6, lane = threadIdx.x & 63;
    const int k = blockIdx.x * 4 + wave;
    const float* wr = w + (size_t)k * DIM;
    float v = wr[lane];
    float s = v * v;
    #pragma unroll
    for (int m = 32; m > 0; m >>= 1) s += __shfl_xor(s, m, 64);
    if (lane == 0) wn[k] = 0.5f * s;
    unsigned int dw = 0;
    #pragma unroll
    for (int t = 0; t < 2; ++t) {
        int spos = 2 * lane + t;          // short position 0..127 in phys row
        int L = spos >> 3, j = spos & 7;  // phys seg, offset
        int Lp = L ^ (k & 15);            // logical seg
        unsigned short val;
        if (Lp < 8) {
            val = f2bf(wr[(Lp << 3) | j]);                 // hi(d)
        } else {
            float vv = wr[((Lp & 7) << 3) | j];
            unsigned short h = f2bf(vv);
            val = f2bf(vv - bf2f(h));                      // lo(d)
        }
        dw |= (unsigned int)val << (16 * t);
    }
    ((unsigned int*)(WEg + (size_t)k * 128))[lane] = dw;   // coalesced 256B/wave
}

// ---------------------------------------------------------------------------
// Main: 512 blocks x 256 thr (2 latent-halves x 2 code-halves). Wave tile
// 64 lats x 64 codes per 128-code chunk; A-frags (negated x) pinned in regs;
// B double-buffered in LDS via async DMA; inline exact rescue; gather.
// LDS map: XE [0,34816) | wbuf1 [34816,67584) | wnl [67584,71680).
// wbuf0 = [0,32768) (aliases XE; first written inside loop iter 0, after
// XE is dead). Epilogue arrays alias [0,19588) (XE/wbuf0, dead post-K).
__global__ __launch_bounds__(256, 2)
void vq_main(const float* __restrict__ x, const float* __restrict__ w,
             const unsigned short* __restrict__ WEg, const float* __restrict__ wn,
             float* __restrict__ out) {
    __shared__ __align__(16) char smem[71680];
    unsigned short* XE = (unsigned short*)smem;        // [128][136] (phase 0 only)
    char* wbuf0 = smem;                                // 32KB B buf (ODD chunks)
    char* wbuf1 = smem + 34816;                        // 32KB B buf (EVEN chunks, no XE alias)
    float* red  = (float*)smem;                        // [32][129] f32 (post-K)
    float* hb1  = (float*)(smem + 16512);              // [2][128] half-reduced score
    int*   hbk  = (int*)(smem + 17536);                // [2][128] half-reduced k
    int*   bfin = (int*)(smem + 18560);                // [128] winner k
    int*   amb  = (int*)(smem + 19072);                // [128] ambiguous lat ids
    int*   ambn = (int*)(smem + 19584);                // count (init in epilogue!)
    float* wnl  = (float*)(smem + 67584);              // [1024] 0.5||w||^2 (whole kernel)

    const int tid  = threadIdx.x;
    const int wave = tid >> 6, lane = tid & 63;
    const int r16  = lane & 15, quad = lane >> 4;
    const int LH = wave & 1, CH = wave >> 1;

    const int blk = blockIdx.x;
    const int b   = blk >> 3;
    const int hw0 = (blk & 7) * LPB;

    // Issue chunk-0 DMA -> wbuf1 IMMEDIATELY (overlaps conversion below).
    {
        const char* gsrc = (const char*)WEg + wave * 8192 + lane * 16;
        char* ldst = wbuf1 + wave * 8192;
        #pragma unroll
        for (int i = 0; i < 8; ++i) async_cp16(gsrc + i * 1024, ldst + i * 1024);
    }

    // Phase 0a: stage wn -> LDS (K-loop then has zero non-DMA vmem).
    wnl[tid]       = wn[tid];
    wnl[tid + 256] = wn[tid + 256];
    wnl[tid + 512] = wn[tid + 512];
    wnl[tid + 768] = wn[tid + 768];

    // Phase 0b: convert NEGATED x tile -> XE[lat][hi 0..63 | lo 64..127].
    {
        const int lat  = tid & 127;
        const int half = tid >> 7;
        const float* xb = x + (size_t)b * (DIM * HW) + hw0 + lat;
        #pragma unroll
        for (int g = 0; g < 4; ++g) {
            short8 hv, lv;
            #pragma unroll
            for (int j = 0; j < 8; ++j) {
                int chn = half * 32 + g * 8 + j;
                float v = -xb[chn * HW];          // negate: score = wn + (-x).w
                unsigned short h = f2bf(v);
                hv[j] = (short)h;
                lv[j] = (short)f2bf(v - bf2f(h));
            }
            *(short8*)&XE[lat * XROW + half * 32 + g * 8]      = hv;
            *(short8*)&XE[lat * XROW + 64 + half * 32 + g * 8] = lv;
        }
    }
    __syncthreads();

    // A-frags: span 0=hi d0-31, 1=hi d32-63, 2=lo d0-31, 3=lo d32-63.
    // (No standalone barrier after this: the ch=0 loop-top barrier is the
    //  XE-death sync; the first wbuf0 write happens after it.)
    short8 areg[4][4];
    #pragma unroll
    for (int lt = 0; lt < 4; ++lt)
        #pragma unroll
        for (int p = 0; p < 4; ++p)
            areg[lt][p] = *(const short8*)&XE[(LH * 64 + lt * 16 + r16) * XROW + p * 32 + quad * 8];

    float b1[16], b2[16];
    #pragma unroll
    for (int sl = 0; sl < 16; ++sl) { b1[sl] = FLT_MAX; b2[sl] = FLT_MAX; }

    #pragma unroll 2
    for (int ch = 0; ch < NCHUNK; ++ch) {
        __syncthreads();   // drains chunk-ch DMA; at ch=0 also = XE-death sync
        if (ch + 1 < NCHUNK) {   // prefetch next chunk into the other buffer
            const char* gsrc = (const char*)WEg + (ch + 1) * 32768 + wave * 8192 + lane * 16;
            char* ldst = (((ch + 1) & 1) ? wbuf0 : wbuf1) + wave * 8192;
            #pragma unroll
            for (int i = 0; i < 8; ++i) async_cp16(gsrc + i * 1024, ldst + i * 1024);
        }
        const char* cbuf = (ch & 1) ? wbuf0 : wbuf1;
        const int kb = ch * CPK;

        float wnv[4];
        #pragma unroll
        for (int ct = 0; ct < 4; ++ct)
            wnv[ct] = wnl[kb + CH * 64 + ct * 16 + r16];
        f32x4 acc[4][4];
        #pragma unroll
        for (int lt = 0; lt < 4; ++lt)
            #pragma unroll
            for (int ct = 0; ct < 4; ++ct) {
                acc[lt][ct][0] = wnv[ct]; acc[lt][ct][1] = wnv[ct];
                acc[lt][ct][2] = wnv[ct]; acc[lt][ct][3] = wnv[ct];
            }

        // 6-step split product (lo*lo dropped; covered by rescue eps).
        // W spans: 0=hi d0-31, 1=hi d32-63, 2=lo d0-31, 3=lo d32-63.
        const int AI[6]  = {0, 1, 0, 2, 1, 3};
        const int WSp[6] = {2, 3, 0, 0, 1, 1};
        short8 bf[4];
        #pragma unroll
        for (int s = 0; s < 6; ++s) {
            if (s == 0 || WSp[s] != WSp[s - 1]) {
                #pragma unroll
                for (int ct = 0; ct < 4; ++ct) {
                    int r = CH * 64 + ct * 16 + r16;
                    int seg = (WSp[s] * 4 + quad) ^ r16;   // matches prep swizzle
                    bf[ct] = *(const short8*)(cbuf + r * 256 + seg * 16);
                }
            }
            #pragma unroll
            for (int lt = 0; lt < 4; ++lt)
                #pragma unroll
                for (int ct = 0; ct < 4; ++ct)
                    acc[lt][ct] = __builtin_amdgcn_mfma_f32_16x16x32_bf16(
                        areg[lt][AI[s]], bf[ct], acc[lt][ct], 0, 0, 0);
        }

        // Fold (3 ops/score): pack vid=(ch<<2)|ct in low 5 mantissa bits
        // (v_and_or); b2 = med3(b1,b2,p) exact top-2 update; b1 = min.
        #pragma unroll
        for (int ct = 0; ct < 4; ++ct) {
            const unsigned vid = (unsigned)((ch << 2) | ct);
            #pragma unroll
            for (int lt = 0; lt < 4; ++lt)
                #pragma unroll
                for (int r = 0; r < 4; ++r) {
                    int sl = lt * 4 + r;
                    float p = __uint_as_float(
                        (__float_as_uint(acc[lt][ct][r]) & 0xFFFFFFE0u) | vid);
                    b2[sl] = __builtin_amdgcn_fmed3f(b1[sl], b2[sl], p);
                    b1[sl] = fminf(b1[sl], p);
                }
        }
    }

    // ---- Epilogue phase 1: argmin over 32 contributors per latent ----
    // Raw (vid-embedded) scores stored; k reconstructed from (vid,cid).
    // Any masked-score tie lands under eps => exact rescue.
    __syncthreads();   // all wbufs dead -> red/hb/amb alias safe
    if (tid == 0) ambn[0] = 0;          // slot aliases XE: init here, post-K
    const int cid = CH * 16 + r16;      // 32 contributors per latent
    int kslot[16];
    #pragma unroll
    for (int lt = 0; lt < 4; ++lt)
        #pragma unroll
        for (int r = 0; r < 4; ++r) {
            int sl = lt * 4 + r;
            unsigned ub = __float_as_uint(b1[sl]);
            int vid = (int)(ub & 31u);
            kslot[sl] = (vid >> 2) * 128 + CH * 64 + (vid & 3) * 16 + r16;
            int lat = LH * 64 + lt * 16 + quad * 4 + r;
            red[cid * 129 + lat] = b1[sl];           // raw, vid kept
        }
    __syncthreads();
    // 2x-parallel: all 256 threads reduce 16 contributors each
    {
        const int lat = tid & 127, hf = tid >> 7;
        const int c0 = hf * 16;
        float s1 = red[c0 * 129 + lat]; int c1 = c0;
        #pragma unroll 4
        for (int c = 1; c < 16; ++c) {
            float s = red[(c0 + c) * 129 + lat];
            if (s < s1) { s1 = s; c1 = c0 + c; }
        }
        unsigned ub = __float_as_uint(s1);
        int vid = (int)(ub & 31u);
        hb1[hf * 128 + lat] = s1;
        hbk[hf * 128 + lat] = (vid >> 2) * 128 + (c1 >> 4) * 64 + (vid & 3) * 16 + (c1 & 15);
    }
    __syncthreads();
    float B1 = 0.f;
    if (tid < LPB) {
        float sA = hb1[tid];       int kA = hbk[tid];
        float sB = hb1[128 + tid]; int kB = hbk[128 + tid];
        if (sB < sA) { sA = sB; kA = kB; }
        B1 = sA; bfin[tid] = kA;
    }
    __syncthreads();
    // Phase 2: global 2nd best = min over (holder-of-winner-k ? b2 : b1)
    #pragma unroll
    for (int lt = 0; lt < 4; ++lt)
        #pragma unroll
        for (int r = 0; r < 4; ++r) {
            int sl = lt * 4 + r;
            int lat = LH * 64 + lt * 16 + quad * 4 + r;
            red[cid * 129 + lat] = (kslot[sl] == bfin[lat]) ? b2[sl] : b1[sl];
        }
    __syncthreads();
    {
        const int lat = tid & 127, hf = tid >> 7;
        float m = red[(hf * 16) * 129 + lat];
        #pragma unroll 4
        for (int c = 1; c < 16; ++c) m = fminf(m, red[(hf * 16 + c) * 129 + lat]);
        hb1[hf * 128 + lat] = m;
    }
    __syncthreads();
    if (tid < LPB) {
        float f2 = fminf(hb1[tid], hb1[128 + tid]);
        // eps: JUSTIFIED error budget of the 6-step split product:
        // split double-rounding residual ~1.2e-4 + dropped lo*lo ~3e-5 typ
        // + vid trunc 2e-6|B1| + fp32 accum 1e-6|B1|. 5e-4+1e-5|B1| is
        // >=3x that bound.
        float eps = 5.0e-4f + 1.0e-5f * fabsf(B1);
        if (f2 - B1 < eps) {
            int pos = atomicAdd(ambn, 1);
            amb[pos] = tid;
        }
    }
    __syncthreads();

    // ---- Inline exact rescue: one wave per ambiguous latent ----
    {
        const int na = ambn[0];
        for (int e = wave; e < na; e += 4) {
            const int lat = amb[e];
            const float* xp = x + (size_t)b * (DIM * HW) + hw0 + lat;
            float xs[DIM];
            #pragma unroll
            for (int d = 0; d < DIM; ++d) xs[d] = xp[d * HW];  // wave-uniform
            float bb = FLT_MAX; int bi = 0;
            #pragma unroll 2
            for (int c = 0; c < 16; ++c) {
                int k = c * 64 + lane;
                const float4* wr = (const float4*)(w + (size_t)k * DIM);
                float a0 = 0.f, a1 = 0.f, a2 = 0.f, a3 = 0.f;
                #pragma unroll
                for (int j = 0; j < 16; ++j) {
                    float4 v = wr[j];
                    a0 += xs[4 * j]     * v.x;  a1 += xs[4 * j + 1] * v.y;
                    a2 += xs[4 * j + 2] * v.z;  a3 += xs[4 * j + 3] * v.w;
                }
                float s = wn[k] - ((a0 + a1) + (a2 + a3));
                if (s < bb) { bb = s; bi = k; }
            }
            #pragma unroll
            for (int off = 32; off > 0; off >>= 1) {   // lex (score,k) argmin
                float ob = __shfl_down(bb, off);
                int   oi = __shfl_down(bi, off);
                if (ob < bb || (ob == bb && oi < bi)) { bb = ob; bi = oi; }
            }
            if (lane == 0) bfin[lat] = bi;
        }
    }
    __syncthreads();

    // ---- Gather: out[n][:] = w[bfin][:]  (coalesced float4) ----
    float* outp = out + (size_t)blk * (LPB * DIM);
    #pragma unroll
    for (int r = 0; r < 8; ++r) {
        int idx = r * 256 + tid;
        int row = idx >> 4, seg = idx & 15;
        int code = bfin[row];
        *(float4*)&outp[idx * 4] = *(const float4*)&w[(size_t)code * DIM + seg * 4];
    }
}

extern "C" void kernel_launch(void* const* d_in, const int* in_sizes, int n_in,
                              void* d_out, int out_size, void* d_ws, size_t ws_size,
                              hipStream_t stream) {
    const float* x = (const float*)d_in[0];
    const float* w = (const float*)d_in[1];
    float* out = (float*)d_out;
    unsigned short* WEg = (unsigned short*)d_ws;                  // 262144 B (swizzled)
    float* wn = (float*)((char*)d_ws + 262144);                   // 4096 B

    vq_prep<<<KCODES / 4, 256, 0, stream>>>(w, WEg, wn);
    vq_main<<<NLAT / LPB, 256, 0, stream>>>(x, w, WEg, wn, out);
}

// Round 14
// 105.648 us; speedup vs baseline: 1.0014x; 1.0014x over previous
//
#include <hip/hip_runtime.h>
#include <hip/hip_bf16.h>
#include <float.h>

// VectorQuantizer: x [64,64,32,32] f32, weight [1024,64] f32
// out[n] = weight[argmin_k ||x_n - w_k||^2]
// score = 0.5||w||^2 + (-x).w via split-bf16 MFMA (6-step, lo*lo dropped).
// R26 = R24 (measured best, 45.0us/105.4 total) + HW bf16 conversion.
// R25 post-mortem: early chunk-0 DMA + coalesced prep = FLAT (46.5-48) =>
// reverted. Session model (3x confirmed): overlap/occupancy changes pay 0;
// instruction removal pays ~proportionally (6-step -4us, eps cut -3.5us,
// dbuf/occupancy/early-DMA all ~0) => issue/work-bound (likely DVFS-low
// clock on short dispatches). So: remove instructions.
//   (1) f2bf body swapped from ~5-op manual RNE bit-twiddle to
//       __float2bfloat16 cast: compiler emits HW v_cvt_pk_bf16_f32
//       (m240: casts compile well; hand-twiddle blocks it). ~3x fewer
//       conversion VALU in phase 0b (320->~120/thread) and vq_prep.
//       RNE => bit-identical on normals; split is self-correcting anyway.
// R24 deltas kept: eps 5e-4+1e-5|B1| (justified bound x3), wnl in LDS,
// unroll 2, 6-step product, short8 XE writes, redk-less epilogue,
// XOR-swizzled staging dbuf, inline exact rescue.
#define NLAT   65536
#define KCODES 1024
#define DIM    64
#define HW     1024
#define LPB    128
#define CPK    128
#define NCHUNK 8
#define XROW   136          // XE padded row (shorts): 272 B

typedef float f32x4 __attribute__((ext_vector_type(4)));
typedef short short8 __attribute__((ext_vector_type(8)));

static __device__ __forceinline__ unsigned short f2bf(float f) {
    __hip_bfloat16 h = __float2bfloat16(f);       // HW RNE (v_cvt_pk_bf16_f32 path)
    return *reinterpret_cast<unsigned short*>(&h);
}
static __device__ __forceinline__ float bf2f(unsigned short h) {
    return __uint_as_float(((unsigned int)h) << 16);
}
static __device__ __forceinline__ void async_cp16(const void* g, void* l) {
    __builtin_amdgcn_global_load_lds(
        (const __attribute__((address_space(1))) unsigned int*)g,
        (__attribute__((address_space(3))) unsigned int*)l, 16, 0, 0);
}

// ---------------------------------------------------------------------------
// Prep: one WAVE per code (grid 256 x 256 thr). Lane d loads w[k][d]
// (coalesced), shuffle-reduces the norm, writes hi/lo shorts into the
// XOR-swizzled row: logical seg L (L<8: hi, L>=8: lo), phys = L ^ (k & 15).
__global__ __launch_bounds__(256)
void vq_prep(const float* __restrict__ w, unsigned short* __restrict__ WEg,
             float* __restrict__ wn) {
    const int wave = threadIdx.x >> 6, lane = threadIdx.x & 63;
    const int k = blockIdx.x * 4 + wave;
    float v = w[(size_t)k * DIM + lane];
    float s = v * v;
    #pragma unroll
    for (int m = 32; m > 0; m >>= 1) s += __shfl_xor(s, m, 64);
    if (lane == 0) wn[k] = 0.5f * s;
    unsigned short h = f2bf(v);
    unsigned short l = f2bf(v - bf2f(h));
    unsigned short* row = WEg + (size_t)k * 128;
    const int j = lane & 7, Lh = lane >> 3, Ll = 8 + (lane >> 3);
    row[(((Lh ^ (k & 15)) << 3) | j)] = h;
    row[(((Ll ^ (k & 15)) << 3) | j)] = l;
}

// ---------------------------------------------------------------------------
// Main: 512 blocks x 256 thr (2 latent-halves x 2 code-halves). Wave tile
// 64 lats x 64 codes per 128-code chunk; A-frags (negated x) pinned in regs;
// B double-buffered in LDS via async DMA; inline exact rescue; gather.
__global__ __launch_bounds__(256, 2)
void vq_main(const float* __restrict__ x, const float* __restrict__ w,
             const unsigned short* __restrict__ WEg, const float* __restrict__ wn,
             float* __restrict__ out) {
    __shared__ __align__(16) char smem[70672];
    unsigned short* XE = (unsigned short*)smem;        // [128][136] (phase 0 only)
    char* wbuf0 = smem;                                // 32KB B buf (even chunks)
    char* wbuf1 = smem + 32768;                        // 32KB B buf (odd chunks)
    float* red  = (float*)smem;                        // [32][129] f32 (post-K)
    float* hb1  = (float*)(smem + 33024);              // [2][128] half-reduced score
    int*   hbk  = (int*)(smem + 34048);                // [2][128] half-reduced k
    int*   bfin = (int*)(smem + 65536);                // [128] winner k
    int*   amb  = (int*)(smem + 66048);                // [128] ambiguous lat ids
    int*   ambn = (int*)(smem + 66560);                // count
    float* wnl  = (float*)(smem + 66576);              // [1024] 0.5||w||^2 (whole kernel)

    const int tid  = threadIdx.x;
    const int wave = tid >> 6, lane = tid & 63;
    const int r16  = lane & 15, quad = lane >> 4;
    const int LH = wave & 1, CH = wave >> 1;

    const int blk = blockIdx.x;
    const int b   = blk >> 3;
    const int hw0 = (blk & 7) * LPB;

    if (tid == 0) ambn[0] = 0;

    // Phase 0a: stage wn -> LDS (K-loop then has zero non-DMA vmem).
    wnl[tid]       = wn[tid];
    wnl[tid + 256] = wn[tid + 256];
    wnl[tid + 512] = wn[tid + 512];
    wnl[tid + 768] = wn[tid + 768];

    // Phase 0b: convert NEGATED x tile -> XE[lat][hi 0..63 | lo 64..127].
    {
        const int lat  = tid & 127;
        const int half = tid >> 7;
        const float* xb = x + (size_t)b * (DIM * HW) + hw0 + lat;
        #pragma unroll
        for (int g = 0; g < 4; ++g) {
            short8 hv, lv;
            #pragma unroll
            for (int j = 0; j < 8; ++j) {
                int chn = half * 32 + g * 8 + j;
                float v = -xb[chn * HW];          // negate: score = wn + (-x).w
                unsigned short h = f2bf(v);
                hv[j] = (short)h;
                lv[j] = (short)f2bf(v - bf2f(h));
            }
            *(short8*)&XE[lat * XROW + half * 32 + g * 8]      = hv;
            *(short8*)&XE[lat * XROW + 64 + half * 32 + g * 8] = lv;
        }
    }
    __syncthreads();

    // A-frags: span 0=hi d0-31, 1=hi d32-63, 2=lo d0-31, 3=lo d32-63
    short8 areg[4][4];
    #pragma unroll
    for (int lt = 0; lt < 4; ++lt)
        #pragma unroll
        for (int p = 0; p < 4; ++p)
            areg[lt][p] = *(const short8*)&XE[(LH * 64 + lt * 16 + r16) * XROW + p * 32 + quad * 8];
    __syncthreads();   // XE dead -> wbuf may overwrite

    // Prefetch chunk 0 into wbuf0 (drained by the first loop-top barrier)
    {
        const char* gsrc = (const char*)WEg + wave * 8192 + lane * 16;
        char* ldst = wbuf0 + wave * 8192;
        #pragma unroll
        for (int i = 0; i < 8; ++i) async_cp16(gsrc + i * 1024, ldst + i * 1024);
    }

    float b1[16], b2[16];
    #pragma unroll
    for (int sl = 0; sl < 16; ++sl) { b1[sl] = FLT_MAX; b2[sl] = FLT_MAX; }

    #pragma unroll 2
    for (int ch = 0; ch < NCHUNK; ++ch) {
        __syncthreads();   // drains chunk-ch DMA (issued one full phase ago)
        if (ch + 1 < NCHUNK) {   // prefetch next chunk into the other buffer
            const char* gsrc = (const char*)WEg + (ch + 1) * 32768 + wave * 8192 + lane * 16;
            char* ldst = (((ch + 1) & 1) ? wbuf1 : wbuf0) + wave * 8192;
            #pragma unroll
            for (int i = 0; i < 8; ++i) async_cp16(gsrc + i * 1024, ldst + i * 1024);
        }
        const char* cbuf = (ch & 1) ? wbuf1 : wbuf0;
        const int kb = ch * CPK;

        float wnv[4];
        #pragma unroll
        for (int ct = 0; ct < 4; ++ct)
            wnv[ct] = wnl[kb + CH * 64 + ct * 16 + r16];
        f32x4 acc[4][4];
        #pragma unroll
        for (int lt = 0; lt < 4; ++lt)
            #pragma unroll
            for (int ct = 0; ct < 4; ++ct) {
                acc[lt][ct][0] = wnv[ct]; acc[lt][ct][1] = wnv[ct];
                acc[lt][ct][2] = wnv[ct]; acc[lt][ct][3] = wnv[ct];
            }

        // 6-step split product (lo*lo dropped; covered by rescue eps).
        // W spans: 0=hi d0-31, 1=hi d32-63, 2=lo d0-31, 3=lo d32-63.
        const int AI[6]  = {0, 1, 0, 2, 1, 3};
        const int WSp[6] = {2, 3, 0, 0, 1, 1};
        short8 bf[4];
        #pragma unroll
        for (int s = 0; s < 6; ++s) {
            if (s == 0 || WSp[s] != WSp[s - 1]) {
                #pragma unroll
                for (int ct = 0; ct < 4; ++ct) {
                    int r = CH * 64 + ct * 16 + r16;
                    int seg = (WSp[s] * 4 + quad) ^ r16;   // matches prep swizzle
                    bf[ct] = *(const short8*)(cbuf + r * 256 + seg * 16);
                }
            }
            #pragma unroll
            for (int lt = 0; lt < 4; ++lt)
                #pragma unroll
                for (int ct = 0; ct < 4; ++ct)
                    acc[lt][ct] = __builtin_amdgcn_mfma_f32_16x16x32_bf16(
                        areg[lt][AI[s]], bf[ct], acc[lt][ct], 0, 0, 0);
        }

        // Fold (3 ops/score): pack vid=(ch<<2)|ct in low 5 mantissa bits;
        // b2 = med3(b1,b2,p) exact top-2 update; b1 = min(b1,p).
        #pragma unroll
        for (int ct = 0; ct < 4; ++ct) {
            const unsigned vid = (unsigned)((ch << 2) | ct);
            #pragma unroll
            for (int lt = 0; lt < 4; ++lt)
                #pragma unroll
                for (int r = 0; r < 4; ++r) {
                    int sl = lt * 4 + r;
                    float p = __uint_as_float(
                        (__float_as_uint(acc[lt][ct][r]) & 0xFFFFFFE0u) | vid);
                    b2[sl] = __builtin_amdgcn_fmed3f(b1[sl], b2[sl], p);
                    b1[sl] = fminf(b1[sl], p);
                }
        }
    }

    // ---- Epilogue phase 1: argmin over 32 contributors per latent ----
    // Raw (vid-embedded) scores stored; k reconstructed from (vid,cid).
    // Any masked-score tie lands under eps => exact rescue.
    __syncthreads();   // wbuf dead -> red alias safe
    const int cid = CH * 16 + r16;   // 32 contributors per latent
    int kslot[16];
    #pragma unroll
    for (int lt = 0; lt < 4; ++lt)
        #pragma unroll
        for (int r = 0; r < 4; ++r) {
            int sl = lt * 4 + r;
            unsigned ub = __float_as_uint(b1[sl]);
            int vid = (int)(ub & 31u);
            kslot[sl] = (vid >> 2) * 128 + CH * 64 + (vid & 3) * 16 + r16;
            int lat = LH * 64 + lt * 16 + quad * 4 + r;
            red[cid * 129 + lat] = b1[sl];           // raw, vid kept
        }
    __syncthreads();
    // 2x-parallel: all 256 threads reduce 16 contributors each
    {
        const int lat = tid & 127, hf = tid >> 7;
        const int c0 = hf * 16;
        float s1 = red[c0 * 129 + lat]; int c1 = c0;
        #pragma unroll 4
        for (int c = 1; c < 16; ++c) {
            float s = red[(c0 + c) * 129 + lat];
            if (s < s1) { s1 = s; c1 = c0 + c; }
        }
        unsigned ub = __float_as_uint(s1);
        int vid = (int)(ub & 31u);
        hb1[hf * 128 + lat] = s1;
        hbk[hf * 128 + lat] = (vid >> 2) * 128 + (c1 >> 4) * 64 + (vid & 3) * 16 + (c1 & 15);
    }
    __syncthreads();
    float B1 = 0.f;
    if (tid < LPB) {
        float sA = hb1[tid];       int kA = hbk[tid];
        float sB = hb1[128 + tid]; int kB = hbk[128 + tid];
        if (sB < sA) { sA = sB; kA = kB; }
        B1 = sA; bfin[tid] = kA;
    }
    __syncthreads();
    // Phase 2: global 2nd best = min over (holder-of-winner-k ? b2 : b1)
    #pragma unroll
    for (int lt = 0; lt < 4; ++lt)
        #pragma unroll
        for (int r = 0; r < 4; ++r) {
            int sl = lt * 4 + r;
            int lat = LH * 64 + lt * 16 + quad * 4 + r;
            red[cid * 129 + lat] = (kslot[sl] == bfin[lat]) ? b2[sl] : b1[sl];
        }
    __syncthreads();
    {
        const int lat = tid & 127, hf = tid >> 7;
        float m = red[(hf * 16) * 129 + lat];
        #pragma unroll 4
        for (int c = 1; c < 16; ++c) m = fminf(m, red[(hf * 16 + c) * 129 + lat]);
        hb1[hf * 128 + lat] = m;
    }
    __syncthreads();
    if (tid < LPB) {
        float f2 = fminf(hb1[tid], hb1[128 + tid]);
        // eps: JUSTIFIED error budget of the 6-step split product:
        // split double-rounding residual ~1.2e-4 + dropped lo*lo ~3e-5 typ
        // + vid trunc 2e-6|B1| + fp32 accum 1e-6|B1|. 5e-4+1e-5|B1| is
        // >=3x that bound.
        float eps = 5.0e-4f + 1.0e-5f * fabsf(B1);
        if (f2 - B1 < eps) {
            int pos = atomicAdd(ambn, 1);
            amb[pos] = tid;
        }
    }
    __syncthreads();

    // ---- Inline exact rescue: one wave per ambiguous latent ----
    {
        const int na = ambn[0];
        for (int e = wave; e < na; e += 4) {
            const int lat = amb[e];
            const float* xp = x + (size_t)b * (DIM * HW) + hw0 + lat;
            float xs[DIM];
            #pragma unroll
            for (int d = 0; d < DIM; ++d) xs[d] = xp[d * HW];  // wave-uniform
            float bb = FLT_MAX; int bi = 0;
            #pragma unroll 2
            for (int c = 0; c < 16; ++c) {
                int k = c * 64 + lane;
                const float4* wr = (const float4*)(w + (size_t)k * DIM);
                float a0 = 0.f, a1 = 0.f, a2 = 0.f, a3 = 0.f;
                #pragma unroll
                for (int j = 0; j < 16; ++j) {
                    float4 v = wr[j];
                    a0 += xs[4 * j]     * v.x;  a1 += xs[4 * j + 1] * v.y;
                    a2 += xs[4 * j + 2] * v.z;  a3 += xs[4 * j + 3] * v.w;
                }
                float s = wn[k] - ((a0 + a1) + (a2 + a3));
                if (s < bb) { bb = s; bi = k; }
            }
            #pragma unroll
            for (int off = 32; off > 0; off >>= 1) {   // lex (score,k) argmin
                float ob = __shfl_down(bb, off);
                int   oi = __shfl_down(bi, off);
                if (ob < bb || (ob == bb && oi < bi)) { bb = ob; bi = oi; }
            }
            if (lane == 0) bfin[lat] = bi;
        }
    }
    __syncthreads();

    // ---- Gather: out[n][:] = w[bfin][:]  (coalesced float4) ----
    float* outp = out + (size_t)blk * (LPB * DIM);
    #pragma unroll
    for (int r = 0; r < 8; ++r) {
        int idx = r * 256 + tid;
        int row = idx >> 4, seg = idx & 15;
        int code = bfin[row];
        *(float4*)&outp[idx * 4] = *(const float4*)&w[(size_t)code * DIM + seg * 4];
    }
}

extern "C" void kernel_launch(void* const* d_in, const int* in_sizes, int n_in,
                              void* d_out, int out_size, void* d_ws, size_t ws_size,
                              hipStream_t stream) {
    const float* x = (const float*)d_in[0];
    const float* w = (const float*)d_in[1];
    float* out = (float*)d_out;
    unsigned short* WEg = (unsigned short*)d_ws;                  // 262144 B (swizzled)
    float* wn = (float*)((char*)d_ws + 262144);                   // 4096 B

    vq_prep<<<KCODES / 4, 256, 0, stream>>>(w, WEg, wn);
    vq_main<<<NLAT / LPB, 256, 0, stream>>>(x, w, WEg, wn, out);
}

// Round 15
// 104.994 us; speedup vs baseline: 1.0076x; 1.0062x over previous
//
#include <hip/hip_runtime.h>
#include <float.h>

// VectorQuantizer: x [64,64,32,32] f32, weight [1024,64] f32
// out[n] = weight[argmin_k ||x_n - w_k||^2]
// score = 0.5||w||^2 + (-x).w via split-bf16 MFMA (6-step, lo*lo dropped).
// R27 = R24 (best, 45.0us profiled / 105.4 total) + FUSED epilogue.
// R26 post-mortem: cast-f2bf ambiguous (profiled +13us but total flat =>
// rocprof clock-state noise); reverted to R24's manual f2bf — one
// variable per round. Session model: issue/work-bound; only instruction
// deletion pays (6-step -4us, eps cut -3.5us; occupancy/overlap all 0).
//   FUSED EPILOGUE (exact): f2 = min(second-min of contributor b1s,
//   b2 of the argmin contributor). Proof: global 2nd-best in a different
//   cell => that cell's b1 == its score (anything smaller would outrank
//   it); in the winner's cell => winner's b2. Deletes kslot (~64 ops),
//   phase-2 select+write (~48), second scan (~32), and 3 barriers; adds
//   b2 store pass (+16), med3 top-2 in scan (+16), 1 dynamic LDS read.
//   Net ~ -110 instr/thread + 3 barrier drains. Ties: raw-equal across
//   cells => f2==B1 => under eps => exact rescue (unchanged).
// R24 deltas kept: eps 5e-4+1e-5|B1| (justified bound x3), wnl in LDS,
// unroll 2, 6-step product, short8 XE writes, XOR-swizzled staging dbuf,
// inline exact rescue.
#define NLAT   65536
#define KCODES 1024
#define DIM    64
#define HW     1024
#define LPB    128
#define CPK    128
#define NCHUNK 8
#define XROW   136          // XE padded row (shorts): 272 B

typedef float f32x4 __attribute__((ext_vector_type(4)));
typedef short short8 __attribute__((ext_vector_type(8)));

static __device__ __forceinline__ unsigned short f2bf(float f) {
    unsigned int u = __float_as_uint(f);
    return (unsigned short)((u + 0x7fffu + ((u >> 16) & 1u)) >> 16);   // RNE
}
static __device__ __forceinline__ float bf2f(unsigned short h) {
    return __uint_as_float(((unsigned int)h) << 16);
}
static __device__ __forceinline__ void async_cp16(const void* g, void* l) {
    __builtin_amdgcn_global_load_lds(
        (const __attribute__((address_space(1))) unsigned int*)g,
        (__attribute__((address_space(3))) unsigned int*)l, 16, 0, 0);
}

// ---------------------------------------------------------------------------
// Prep: one WAVE per code (grid 256 x 256 thr). Lane d loads w[k][d]
// (coalesced), shuffle-reduces the norm, writes hi/lo shorts into the
// XOR-swizzled row: logical seg L (L<8: hi, L>=8: lo), phys = L ^ (k & 15).
__global__ __launch_bounds__(256)
void vq_prep(const float* __restrict__ w, unsigned short* __restrict__ WEg,
             float* __restrict__ wn) {
    const int wave = threadIdx.x >> 6, lane = threadIdx.x & 63;
    const int k = blockIdx.x * 4 + wave;
    float v = w[(size_t)k * DIM + lane];
    float s = v * v;
    #pragma unroll
    for (int m = 32; m > 0; m >>= 1) s += __shfl_xor(s, m, 64);
    if (lane == 0) wn[k] = 0.5f * s;
    unsigned short h = f2bf(v);
    unsigned short l = f2bf(v - bf2f(h));
    unsigned short* row = WEg + (size_t)k * 128;
    const int j = lane & 7, Lh = lane >> 3, Ll = 8 + (lane >> 3);
    row[(((Lh ^ (k & 15)) << 3) | j)] = h;
    row[(((Ll ^ (k & 15)) << 3) | j)] = l;
}

// ---------------------------------------------------------------------------
// Main: 512 blocks x 256 thr (2 latent-halves x 2 code-halves). Wave tile
// 64 lats x 64 codes per 128-code chunk; A-frags (negated x) pinned in regs;
// B double-buffered in LDS via async DMA; fused epilogue; inline exact
// rescue; gather.
__global__ __launch_bounds__(256, 2)
void vq_main(const float* __restrict__ x, const float* __restrict__ w,
             const unsigned short* __restrict__ WEg, const float* __restrict__ wn,
             float* __restrict__ out) {
    __shared__ __align__(16) char smem[70672];
    unsigned short* XE = (unsigned short*)smem;        // [128][136] (phase 0 only)
    char* wbuf0 = smem;                                // 32KB B buf (even chunks)
    char* wbuf1 = smem + 32768;                        // 32KB B buf (odd chunks)
    float* redA = (float*)smem;                        // [32][129] b1 (post-K)
    float* redB = (float*)(smem + 16512);              // [32][129] b2 (post-K)
    float* hb1  = (float*)(smem + 33024);              // [2][128] half-best score
    int*   hbk  = (int*)(smem + 34048);                // [2][128] half-best k
    float* hb2  = (float*)(smem + 35072);              // [2][128] half 2nd-best
    int*   bfin = (int*)(smem + 65536);                // [128] winner k
    int*   amb  = (int*)(smem + 66048);                // [128] ambiguous lat ids
    int*   ambn = (int*)(smem + 66560);                // count
    float* wnl  = (float*)(smem + 66576);              // [1024] 0.5||w||^2 (whole kernel)

    const int tid  = threadIdx.x;
    const int wave = tid >> 6, lane = tid & 63;
    const int r16  = lane & 15, quad = lane >> 4;
    const int LH = wave & 1, CH = wave >> 1;

    const int blk = blockIdx.x;
    const int b   = blk >> 3;
    const int hw0 = (blk & 7) * LPB;

    if (tid == 0) ambn[0] = 0;

    // Phase 0a: stage wn -> LDS (K-loop then has zero non-DMA vmem).
    wnl[tid]       = wn[tid];
    wnl[tid + 256] = wn[tid + 256];
    wnl[tid + 512] = wn[tid + 512];
    wnl[tid + 768] = wn[tid + 768];

    // Phase 0b: convert NEGATED x tile -> XE[lat][hi 0..63 | lo 64..127].
    {
        const int lat  = tid & 127;
        const int half = tid >> 7;
        const float* xb = x + (size_t)b * (DIM * HW) + hw0 + lat;
        #pragma unroll
        for (int g = 0; g < 4; ++g) {
            short8 hv, lv;
            #pragma unroll
            for (int j = 0; j < 8; ++j) {
                int chn = half * 32 + g * 8 + j;
                float v = -xb[chn * HW];          // negate: score = wn + (-x).w
                unsigned short h = f2bf(v);
                hv[j] = (short)h;
                lv[j] = (short)f2bf(v - bf2f(h));
            }
            *(short8*)&XE[lat * XROW + half * 32 + g * 8]      = hv;
            *(short8*)&XE[lat * XROW + 64 + half * 32 + g * 8] = lv;
        }
    }
    __syncthreads();

    // A-frags: span 0=hi d0-31, 1=hi d32-63, 2=lo d0-31, 3=lo d32-63
    short8 areg[4][4];
    #pragma unroll
    for (int lt = 0; lt < 4; ++lt)
        #pragma unroll
        for (int p = 0; p < 4; ++p)
            areg[lt][p] = *(const short8*)&XE[(LH * 64 + lt * 16 + r16) * XROW + p * 32 + quad * 8];
    __syncthreads();   // XE dead -> wbuf may overwrite

    // Prefetch chunk 0 into wbuf0 (drained by the first loop-top barrier)
    {
        const char* gsrc = (const char*)WEg + wave * 8192 + lane * 16;
        char* ldst = wbuf0 + wave * 8192;
        #pragma unroll
        for (int i = 0; i < 8; ++i) async_cp16(gsrc + i * 1024, ldst + i * 1024);
    }

    float b1[16], b2[16];
    #pragma unroll
    for (int sl = 0; sl < 16; ++sl) { b1[sl] = FLT_MAX; b2[sl] = FLT_MAX; }

    #pragma unroll 2
    for (int ch = 0; ch < NCHUNK; ++ch) {
        __syncthreads();   // drains chunk-ch DMA (issued one full phase ago)
        if (ch + 1 < NCHUNK) {   // prefetch next chunk into the other buffer
            const char* gsrc = (const char*)WEg + (ch + 1) * 32768 + wave * 8192 + lane * 16;
            char* ldst = (((ch + 1) & 1) ? wbuf1 : wbuf0) + wave * 8192;
            #pragma unroll
            for (int i = 0; i < 8; ++i) async_cp16(gsrc + i * 1024, ldst + i * 1024);
        }
        const char* cbuf = (ch & 1) ? wbuf1 : wbuf0;
        const int kb = ch * CPK;

        float wnv[4];
        #pragma unroll
        for (int ct = 0; ct < 4; ++ct)
            wnv[ct] = wnl[kb + CH * 64 + ct * 16 + r16];
        f32x4 acc[4][4];
        #pragma unroll
        for (int lt = 0; lt < 4; ++lt)
            #pragma unroll
            for (int ct = 0; ct < 4; ++ct) {
                acc[lt][ct][0] = wnv[ct]; acc[lt][ct][1] = wnv[ct];
                acc[lt][ct][2] = wnv[ct]; acc[lt][ct][3] = wnv[ct];
            }

        // 6-step split product (lo*lo dropped; covered by rescue eps).
        // W spans: 0=hi d0-31, 1=hi d32-63, 2=lo d0-31, 3=lo d32-63.
        const int AI[6]  = {0, 1, 0, 2, 1, 3};
        const int WSp[6] = {2, 3, 0, 0, 1, 1};
        short8 bf[4];
        #pragma unroll
        for (int s = 0; s < 6; ++s) {
            if (s == 0 || WSp[s] != WSp[s - 1]) {
                #pragma unroll
                for (int ct = 0; ct < 4; ++ct) {
                    int r = CH * 64 + ct * 16 + r16;
                    int seg = (WSp[s] * 4 + quad) ^ r16;   // matches prep swizzle
                    bf[ct] = *(const short8*)(cbuf + r * 256 + seg * 16);
                }
            }
            #pragma unroll
            for (int lt = 0; lt < 4; ++lt)
                #pragma unroll
                for (int ct = 0; ct < 4; ++ct)
                    acc[lt][ct] = __builtin_amdgcn_mfma_f32_16x16x32_bf16(
                        areg[lt][AI[s]], bf[ct], acc[lt][ct], 0, 0, 0);
        }

        // Fold (3 ops/score): pack vid=(ch<<2)|ct in low 5 mantissa bits;
        // b2 = med3(b1,b2,p) exact top-2 update; b1 = min(b1,p).
        #pragma unroll
        for (int ct = 0; ct < 4; ++ct) {
            const unsigned vid = (unsigned)((ch << 2) | ct);
            #pragma unroll
            for (int lt = 0; lt < 4; ++lt)
                #pragma unroll
                for (int r = 0; r < 4; ++r) {
                    int sl = lt * 4 + r;
                    float p = __uint_as_float(
                        (__float_as_uint(acc[lt][ct][r]) & 0xFFFFFFE0u) | vid);
                    b2[sl] = __builtin_amdgcn_fmed3f(b1[sl], b2[sl], p);
                    b1[sl] = fminf(b1[sl], p);
                }
        }
    }

    // ---- FUSED epilogue: one scan computes winner AND exact 2nd-best ----
    // f2 = min(second-min of contributor b1s, b2 of argmin contributor).
    // 2nd-best in another cell => that cell's b1 == its score; in the
    // winner's cell => winner's b2. Raw ties => f2==B1 => rescued.
    __syncthreads();   // wbuf dead -> redA/redB alias safe
    const int cid = CH * 16 + r16;   // 32 contributors per latent
    #pragma unroll
    for (int lt = 0; lt < 4; ++lt)
        #pragma unroll
        for (int r = 0; r < 4; ++r) {
            int sl = lt * 4 + r;
            int lat = LH * 64 + lt * 16 + quad * 4 + r;
            redA[cid * 129 + lat] = b1[sl];          // raw, vid kept
            redB[cid * 129 + lat] = b2[sl];
        }
    __syncthreads();
    // 2x-parallel fused scan: 16 contributors each, top-2 + winner's b2
    {
        const int lat = tid & 127, hf = tid >> 7;
        const int c0 = hf * 16;
        float m1 = redA[c0 * 129 + lat]; int c1 = c0;
        float m2 = FLT_MAX;
        #pragma unroll 4
        for (int c = 1; c < 16; ++c) {
            float v = redA[(c0 + c) * 129 + lat];
            m2 = __builtin_amdgcn_fmed3f(m1, m2, v);   // exact top-2 update
            if (v < m1) { m1 = v; c1 = c0 + c; }
        }
        float f2h = fminf(m2, redB[c1 * 129 + lat]);   // same-cell top-2 cover
        unsigned ub = __float_as_uint(m1);
        int vid = (int)(ub & 31u);
        hb1[hf * 128 + lat] = m1;
        hbk[hf * 128 + lat] = (vid >> 2) * 128 + (c1 >> 4) * 64 + (vid & 3) * 16 + (c1 & 15);
        hb2[hf * 128 + lat] = f2h;
    }
    __syncthreads();
    if (tid < LPB) {
        float sA = hb1[tid], sB = hb1[128 + tid];
        float B1, f2; int kW;
        if (sB < sA) { B1 = sB; kW = hbk[128 + tid]; f2 = fminf(hb2[128 + tid], sA); }
        else         { B1 = sA; kW = hbk[tid];       f2 = fminf(hb2[tid], sB); }
        bfin[tid] = kW;
        // eps: JUSTIFIED error budget of the 6-step split product:
        // split double-rounding residual ~1.2e-4 + dropped lo*lo ~3e-5 typ
        // + vid trunc 2e-6|B1| + fp32 accum 1e-6|B1|. 5e-4+1e-5|B1| is
        // >=3x that bound.
        float eps = 5.0e-4f + 1.0e-5f * fabsf(B1);
        if (f2 - B1 < eps) {
            int pos = atomicAdd(ambn, 1);
            amb[pos] = tid;
        }
    }
    __syncthreads();

    // ---- Inline exact rescue: one wave per ambiguous latent ----
    {
        const int na = ambn[0];
        for (int e = wave; e < na; e += 4) {
            const int lat = amb[e];
            const float* xp = x + (size_t)b * (DIM * HW) + hw0 + lat;
            float xs[DIM];
            #pragma unroll
            for (int d = 0; d < DIM; ++d) xs[d] = xp[d * HW];  // wave-uniform
            float bb = FLT_MAX; int bi = 0;
            #pragma unroll 2
            for (int c = 0; c < 16; ++c) {
                int k = c * 64 + lane;
                const float4* wr = (const float4*)(w + (size_t)k * DIM);
                float a0 = 0.f, a1 = 0.f, a2 = 0.f, a3 = 0.f;
                #pragma unroll
                for (int j = 0; j < 16; ++j) {
                    float4 v = wr[j];
                    a0 += xs[4 * j]     * v.x;  a1 += xs[4 * j + 1] * v.y;
                    a2 += xs[4 * j + 2] * v.z;  a3 += xs[4 * j + 3] * v.w;
                }
                float s = wn[k] - ((a0 + a1) + (a2 + a3));
                if (s < bb) { bb = s; bi = k; }
            }
            #pragma unroll
            for (int off = 32; off > 0; off >>= 1) {   // lex (score,k) argmin
                float ob = __shfl_down(bb, off);
                int   oi = __shfl_down(bi, off);
                if (ob < bb || (ob == bb && oi < bi)) { bb = ob; bi = oi; }
            }
            if (lane == 0) bfin[lat] = bi;
        }
    }
    __syncthreads();

    // ---- Gather: out[n][:] = w[bfin][:]  (coalesced float4) ----
    float* outp = out + (size_t)blk * (LPB * DIM);
    #pragma unroll
    for (int r = 0; r < 8; ++r) {
        int idx = r * 256 + tid;
        int row = idx >> 4, seg = idx & 15;
        int code = bfin[row];
        *(float4*)&outp[idx * 4] = *(const float4*)&w[(size_t)code * DIM + seg * 4];
    }
}

extern "C" void kernel_launch(void* const* d_in, const int* in_sizes, int n_in,
                              void* d_out, int out_size, void* d_ws, size_t ws_size,
                              hipStream_t stream) {
    const float* x = (const float*)d_in[0];
    const float* w = (const float*)d_in[1];
    float* out = (float*)d_out;
    unsigned short* WEg = (unsigned short*)d_ws;                  // 262144 B (swizzled)
    float* wn = (float*)((char*)d_ws + 262144);                   // 4096 B

    vq_prep<<<KCODES / 4, 256, 0, stream>>>(w, WEg, wn);
    vq_main<<<NLAT / LPB, 256, 0, stream>>>(x, w, WEg, wn, out);
}

// Round 16
// 103.463 us; speedup vs baseline: 1.0226x; 1.0148x over previous
//
#include <hip/hip_runtime.h>
#include <float.h>

// VectorQuantizer: x [64,64,32,32] f32, weight [1024,64] f32
// out[n] = weight[argmin_k ||x_n - w_k||^2]
// score = 0.5||w||^2 + (-x).w via split-bf16 MFMA (6-step, lo*lo dropped).
// R28 = R27 (best, 44.3-46.0us / 105.0 total) + B-frag load pipeline + eps.
// R27 post-mortem: fused epilogue ~ -0.5us (prop. to instr cut). KEY:
// fillBufferAligned hit 6 TB/s in-stream => clocks are FULL => 44.5us =
// ~107k cy; per-chunk work model accounts ~2.2k of ~13k cy/chunk => ~6x
// unexplained stall. Prime suspect: ds_read->MFMA dep latency (16 B-frag
// loads/chunk issued right before consumers, ~120cy LDS latency, only 2
// waves/SIMD to cover; our MFMA density is 1/4 of m97-GEMM so compiler
// scheduling has less room).
//   (1) B-frag SW pipeline, one group ahead (bfA/bfB reg dbuf): span2+3
//       groups issued before acc-init; each group reloaded under the other
//       group's 16 MFMAs (~78cy dep distance). Same 6 products, same
//       per-acc order => bit-identical. +16 VGPR (~204 total, <256 budget).
//   (2) eps 5e-4+1e-5|B1| -> 4e-4+8e-6|B1| (margin 3x->2.3x of analyzed
//       bound ~2.8e-4@|B1|=30; missed-rescue would fail absmax loudly).
// Kept: fused epilogue (f2 = min(2nd-min of cell-b1s, winner-cell b2)),
// eps-justified rescue, wnl in LDS, unroll 2, 6-step product, short8 XE,
// XOR-swizzled staging dbuf, inline exact rescue.
// If flat: structure floor ~44.5us documented; R27/R28 final.
#define NLAT   65536
#define KCODES 1024
#define DIM    64
#define HW     1024
#define LPB    128
#define CPK    128
#define NCHUNK 8
#define XROW   136          // XE padded row (shorts): 272 B

typedef float f32x4 __attribute__((ext_vector_type(4)));
typedef short short8 __attribute__((ext_vector_type(8)));

static __device__ __forceinline__ unsigned short f2bf(float f) {
    unsigned int u = __float_as_uint(f);
    return (unsigned short)((u + 0x7fffu + ((u >> 16) & 1u)) >> 16);   // RNE
}
static __device__ __forceinline__ float bf2f(unsigned short h) {
    return __uint_as_float(((unsigned int)h) << 16);
}
static __device__ __forceinline__ void async_cp16(const void* g, void* l) {
    __builtin_amdgcn_global_load_lds(
        (const __attribute__((address_space(1))) unsigned int*)g,
        (__attribute__((address_space(3))) unsigned int*)l, 16, 0, 0);
}

// ---------------------------------------------------------------------------
// Prep: one WAVE per code (grid 256 x 256 thr). Lane d loads w[k][d]
// (coalesced), shuffle-reduces the norm, writes hi/lo shorts into the
// XOR-swizzled row: logical seg L (L<8: hi, L>=8: lo), phys = L ^ (k & 15).
__global__ __launch_bounds__(256)
void vq_prep(const float* __restrict__ w, unsigned short* __restrict__ WEg,
             float* __restrict__ wn) {
    const int wave = threadIdx.x >> 6, lane = threadIdx.x & 63;
    const int k = blockIdx.x * 4 + wave;
    float v = w[(size_t)k * DIM + lane];
    float s = v * v;
    #pragma unroll
    for (int m = 32; m > 0; m >>= 1) s += __shfl_xor(s, m, 64);
    if (lane == 0) wn[k] = 0.5f * s;
    unsigned short h = f2bf(v);
    unsigned short l = f2bf(v - bf2f(h));
    unsigned short* row = WEg + (size_t)k * 128;
    const int j = lane & 7, Lh = lane >> 3, Ll = 8 + (lane >> 3);
    row[(((Lh ^ (k & 15)) << 3) | j)] = h;
    row[(((Ll ^ (k & 15)) << 3) | j)] = l;
}

// B-fragment group load: one LDS row base per ct, shared seg per span.
#define LOADG(b0, b1, b2, b3, span) do {                                  \
    const int seg_ = ((((span) * 4) + quad) ^ r16) * 16;                  \
    const char* base_ = cbuf + (size_t)(CH * 64 + r16) * 256 + seg_;      \
    b0 = *(const short8*)(base_);                                         \
    b1 = *(const short8*)(base_ + 16 * 256);                              \
    b2 = *(const short8*)(base_ + 32 * 256);                              \
    b3 = *(const short8*)(base_ + 48 * 256);                              \
} while (0)

#define MMAG(ai, b0, b1, b2, b3) do {                                     \
    _Pragma("unroll")                                                     \
    for (int lt = 0; lt < 4; ++lt) {                                      \
        acc[lt][0] = __builtin_amdgcn_mfma_f32_16x16x32_bf16(             \
            areg[lt][ai], b0, acc[lt][0], 0, 0, 0);                       \
        acc[lt][1] = __builtin_amdgcn_mfma_f32_16x16x32_bf16(             \
            areg[lt][ai], b1, acc[lt][1], 0, 0, 0);                       \
        acc[lt][2] = __builtin_amdgcn_mfma_f32_16x16x32_bf16(             \
            areg[lt][ai], b2, acc[lt][2], 0, 0, 0);                       \
        acc[lt][3] = __builtin_amdgcn_mfma_f32_16x16x32_bf16(             \
            areg[lt][ai], b3, acc[lt][3], 0, 0, 0);                       \
    }                                                                     \
} while (0)

// ---------------------------------------------------------------------------
// Main: 512 blocks x 256 thr (2 latent-halves x 2 code-halves). Wave tile
// 64 lats x 64 codes per 128-code chunk; A-frags (negated x) pinned in regs;
// B double-buffered in LDS via async DMA; B-frag reg pipeline; fused
// epilogue; inline exact rescue; gather.
__global__ __launch_bounds__(256, 2)
void vq_main(const float* __restrict__ x, const float* __restrict__ w,
             const unsigned short* __restrict__ WEg, const float* __restrict__ wn,
             float* __restrict__ out) {
    __shared__ __align__(16) char smem[70672];
    unsigned short* XE = (unsigned short*)smem;        // [128][136] (phase 0 only)
    char* wbuf0 = smem;                                // 32KB B buf (even chunks)
    char* wbuf1 = smem + 32768;                        // 32KB B buf (odd chunks)
    float* redA = (float*)smem;                        // [32][129] b1 (post-K)
    float* redB = (float*)(smem + 16512);              // [32][129] b2 (post-K)
    float* hb1  = (float*)(smem + 33024);              // [2][128] half-best score
    int*   hbk  = (int*)(smem + 34048);                // [2][128] half-best k
    float* hb2  = (float*)(smem + 35072);              // [2][128] half 2nd-best
    int*   bfin = (int*)(smem + 65536);                // [128] winner k
    int*   amb  = (int*)(smem + 66048);                // [128] ambiguous lat ids
    int*   ambn = (int*)(smem + 66560);                // count
    float* wnl  = (float*)(smem + 66576);              // [1024] 0.5||w||^2 (whole kernel)

    const int tid  = threadIdx.x;
    const int wave = tid >> 6, lane = tid & 63;
    const int r16  = lane & 15, quad = lane >> 4;
    const int LH = wave & 1, CH = wave >> 1;

    const int blk = blockIdx.x;
    const int b   = blk >> 3;
    const int hw0 = (blk & 7) * LPB;

    if (tid == 0) ambn[0] = 0;

    // Phase 0a: stage wn -> LDS (K-loop then has zero non-DMA vmem).
    wnl[tid]       = wn[tid];
    wnl[tid + 256] = wn[tid + 256];
    wnl[tid + 512] = wn[tid + 512];
    wnl[tid + 768] = wn[tid + 768];

    // Phase 0b: convert NEGATED x tile -> XE[lat][hi 0..63 | lo 64..127].
    {
        const int lat  = tid & 127;
        const int half = tid >> 7;
        const float* xb = x + (size_t)b * (DIM * HW) + hw0 + lat;
        #pragma unroll
        for (int g = 0; g < 4; ++g) {
            short8 hv, lv;
            #pragma unroll
            for (int j = 0; j < 8; ++j) {
                int chn = half * 32 + g * 8 + j;
                float v = -xb[chn * HW];          // negate: score = wn + (-x).w
                unsigned short h = f2bf(v);
                hv[j] = (short)h;
                lv[j] = (short)f2bf(v - bf2f(h));
            }
            *(short8*)&XE[lat * XROW + half * 32 + g * 8]      = hv;
            *(short8*)&XE[lat * XROW + 64 + half * 32 + g * 8] = lv;
        }
    }
    __syncthreads();

    // A-frags: span 0=hi d0-31, 1=hi d32-63, 2=lo d0-31, 3=lo d32-63
    short8 areg[4][4];
    #pragma unroll
    for (int lt = 0; lt < 4; ++lt)
        #pragma unroll
        for (int p = 0; p < 4; ++p)
            areg[lt][p] = *(const short8*)&XE[(LH * 64 + lt * 16 + r16) * XROW + p * 32 + quad * 8];
    __syncthreads();   // XE dead -> wbuf may overwrite

    // Prefetch chunk 0 into wbuf0 (drained by the first loop-top barrier)
    {
        const char* gsrc = (const char*)WEg + wave * 8192 + lane * 16;
        char* ldst = wbuf0 + wave * 8192;
        #pragma unroll
        for (int i = 0; i < 8; ++i) async_cp16(gsrc + i * 1024, ldst + i * 1024);
    }

    float b1[16], b2[16];
    #pragma unroll
    for (int sl = 0; sl < 16; ++sl) { b1[sl] = FLT_MAX; b2[sl] = FLT_MAX; }

    #pragma unroll 2
    for (int ch = 0; ch < NCHUNK; ++ch) {
        __syncthreads();   // drains chunk-ch DMA (issued one full phase ago)
        if (ch + 1 < NCHUNK) {   // prefetch next chunk into the other buffer
            const char* gsrc = (const char*)WEg + (ch + 1) * 32768 + wave * 8192 + lane * 16;
            char* ldst = (((ch + 1) & 1) ? wbuf1 : wbuf0) + wave * 8192;
            #pragma unroll
            for (int i = 0; i < 8; ++i) async_cp16(gsrc + i * 1024, ldst + i * 1024);
        }
        const char* cbuf = (ch & 1) ? wbuf1 : wbuf0;
        const int kb = ch * CPK;

        // Issue the first two B-frag groups EARLY (latency hides under
        // wnv read + acc-init), then keep one group in flight behind the
        // other group's 16 MFMAs. Same 6 products, same per-acc order as
        // the rolled loop => bit-identical accumulation.
        short8 bfA0, bfA1, bfA2, bfA3, bfB0, bfB1, bfB2, bfB3;
        LOADG(bfA0, bfA1, bfA2, bfA3, 2);
        LOADG(bfB0, bfB1, bfB2, bfB3, 3);

        float wnv[4];
        #pragma unroll
        for (int ct = 0; ct < 4; ++ct)
            wnv[ct] = wnl[kb + CH * 64 + ct * 16 + r16];
        f32x4 acc[4][4];
        #pragma unroll
        for (int lt = 0; lt < 4; ++lt)
            #pragma unroll
            for (int ct = 0; ct < 4; ++ct) {
                acc[lt][ct][0] = wnv[ct]; acc[lt][ct][1] = wnv[ct];
                acc[lt][ct][2] = wnv[ct]; acc[lt][ct][3] = wnv[ct];
            }

        MMAG(0, bfA0, bfA1, bfA2, bfA3);   // s0: A0 x W2 (hi.lo d0-31)
        LOADG(bfA0, bfA1, bfA2, bfA3, 0);  // span0 in flight under s1
        MMAG(1, bfB0, bfB1, bfB2, bfB3);   // s1: A1 x W3 (hi.lo d32-63)
        LOADG(bfB0, bfB1, bfB2, bfB3, 1);  // span1 in flight under s2/s3
        MMAG(0, bfA0, bfA1, bfA2, bfA3);   // s2: A0 x W0 (hi.hi d0-31)
        MMAG(2, bfA0, bfA1, bfA2, bfA3);   // s3: A2 x W0 (lo.hi d0-31)
        MMAG(1, bfB0, bfB1, bfB2, bfB3);   // s4: A1 x W1 (hi.hi d32-63)
        MMAG(3, bfB0, bfB1, bfB2, bfB3);   // s5: A3 x W1 (lo.hi d32-63)

        // Fold (3 ops/score): pack vid=(ch<<2)|ct in low 5 mantissa bits;
        // b2 = med3(b1,b2,p) exact top-2 update; b1 = min(b1,p).
        #pragma unroll
        for (int ct = 0; ct < 4; ++ct) {
            const unsigned vid = (unsigned)((ch << 2) | ct);
            #pragma unroll
            for (int lt = 0; lt < 4; ++lt)
                #pragma unroll
                for (int r = 0; r < 4; ++r) {
                    int sl = lt * 4 + r;
                    float p = __uint_as_float(
                        (__float_as_uint(acc[lt][ct][r]) & 0xFFFFFFE0u) | vid);
                    b2[sl] = __builtin_amdgcn_fmed3f(b1[sl], b2[sl], p);
                    b1[sl] = fminf(b1[sl], p);
                }
        }
    }

    // ---- FUSED epilogue: one scan computes winner AND exact 2nd-best ----
    // f2 = min(second-min of contributor b1s, b2 of argmin contributor).
    // 2nd-best in another cell => that cell's b1 == its score; in the
    // winner's cell => winner's b2. Raw ties => f2==B1 => rescued.
    __syncthreads();   // wbuf dead -> redA/redB alias safe
    const int cid = CH * 16 + r16;   // 32 contributors per latent
    #pragma unroll
    for (int lt = 0; lt < 4; ++lt)
        #pragma unroll
        for (int r = 0; r < 4; ++r) {
            int sl = lt * 4 + r;
            int lat = LH * 64 + lt * 16 + quad * 4 + r;
            redA[cid * 129 + lat] = b1[sl];          // raw, vid kept
            redB[cid * 129 + lat] = b2[sl];
        }
    __syncthreads();
    // 2x-parallel fused scan: 16 contributors each, top-2 + winner's b2
    {
        const int lat = tid & 127, hf = tid >> 7;
        const int c0 = hf * 16;
        float m1 = redA[c0 * 129 + lat]; int c1 = c0;
        float m2 = FLT_MAX;
        #pragma unroll 4
        for (int c = 1; c < 16; ++c) {
            float v = redA[(c0 + c) * 129 + lat];
            m2 = __builtin_amdgcn_fmed3f(m1, m2, v);   // exact top-2 update
            if (v < m1) { m1 = v; c1 = c0 + c; }
        }
        float f2h = fminf(m2, redB[c1 * 129 + lat]);   // same-cell top-2 cover
        unsigned ub = __float_as_uint(m1);
        int vid = (int)(ub & 31u);
        hb1[hf * 128 + lat] = m1;
        hbk[hf * 128 + lat] = (vid >> 2) * 128 + (c1 >> 4) * 64 + (vid & 3) * 16 + (c1 & 15);
        hb2[hf * 128 + lat] = f2h;
    }
    __syncthreads();
    if (tid < LPB) {
        float sA = hb1[tid], sB = hb1[128 + tid];
        float B1, f2; int kW;
        if (sB < sA) { B1 = sB; kW = hbk[128 + tid]; f2 = fminf(hb2[128 + tid], sA); }
        else         { B1 = sA; kW = hbk[tid];       f2 = fminf(hb2[tid], sB); }
        bfin[tid] = kW;
        // eps: analyzed error budget ~ (1.3e-4 lo*lo tail + 2e-5 split
        // rounding + 1e-5 accum) + ~4e-6|B1| trunc ~ 2.8e-4 @|B1|=30.
        // 4e-4 + 8e-6|B1| keeps >=2.3x margin (was 3x).
        float eps = 4.0e-4f + 8.0e-6f * fabsf(B1);
        if (f2 - B1 < eps) {
            int pos = atomicAdd(ambn, 1);
            amb[pos] = tid;
        }
    }
    __syncthreads();

    // ---- Inline exact rescue: one wave per ambiguous latent ----
    {
        const int na = ambn[0];
        for (int e = wave; e < na; e += 4) {
            const int lat = amb[e];
            const float* xp = x + (size_t)b * (DIM * HW) + hw0 + lat;
            float xs[DIM];
            #pragma unroll
            for (int d = 0; d < DIM; ++d) xs[d] = xp[d * HW];  // wave-uniform
            float bb = FLT_MAX; int bi = 0;
            #pragma unroll 2
            for (int c = 0; c < 16; ++c) {
                int k = c * 64 + lane;
                const float4* wr = (const float4*)(w + (size_t)k * DIM);
                float a0 = 0.f, a1 = 0.f, a2 = 0.f, a3 = 0.f;
                #pragma unroll
                for (int j = 0; j < 16; ++j) {
                    float4 v = wr[j];
                    a0 += xs[4 * j]     * v.x;  a1 += xs[4 * j + 1] * v.y;
                    a2 += xs[4 * j + 2] * v.z;  a3 += xs[4 * j + 3] * v.w;
                }
                float s = wn[k] - ((a0 + a1) + (a2 + a3));
                if (s < bb) { bb = s; bi = k; }
            }
            #pragma unroll
            for (int off = 32; off > 0; off >>= 1) {   // lex (score,k) argmin
                float ob = __shfl_down(bb, off);
                int   oi = __shfl_down(bi, off);
                if (ob < bb || (ob == bb && oi < bi)) { bb = ob; bi = oi; }
            }
            if (lane == 0) bfin[lat] = bi;
        }
    }
    __syncthreads();

    // ---- Gather: out[n][:] = w[bfin][:]  (coalesced float4) ----
    float* outp = out + (size_t)blk * (LPB * DIM);
    #pragma unroll
    for (int r = 0; r < 8; ++r) {
        int idx = r * 256 + tid;
        int row = idx >> 4, seg = idx & 15;
        int code = bfin[row];
        *(float4*)&outp[idx * 4] = *(const float4*)&w[(size_t)code * DIM + seg * 4];
    }
}

extern "C" void kernel_launch(void* const* d_in, const int* in_sizes, int n_in,
                              void* d_out, int out_size, void* d_ws, size_t ws_size,
                              hipStream_t stream) {
    const float* x = (const float*)d_in[0];
    const float* w = (const float*)d_in[1];
    float* out = (float*)d_out;
    unsigned short* WEg = (unsigned short*)d_ws;                  // 262144 B (swizzled)
    float* wn = (float*)((char*)d_ws + 262144);                   // 4096 B

    vq_prep<<<KCODES / 4, 256, 0, stream>>>(w, WEg, wn);
    vq_main<<<NLAT / LPB, 256, 0, stream>>>(x, w, WEg, wn, out);
}